// Round 6
// baseline (263.247 us; speedup 1.0000x reference)
//
#include <hip/hip_runtime.h>

#define Bb 32
#define Nn 512
#define Dd 256
#define KC 1792   // 256 (self) + 6*256 (edge types)

typedef __bf16 bf16x8 __attribute__((ext_vector_type(8)));
typedef float  f32x4  __attribute__((ext_vector_type(4)));
typedef unsigned short u16;

__device__ __forceinline__ u16 f2bf(float x){
  union { float f; unsigned u; } c; c.f = x;
  unsigned u = c.u;
  u += 0x7FFFu + ((u >> 16) & 1u);   // RNE
  return (u16)(u >> 16);
}

// ---------------- K0: WcatT[e][c] = Wcat[c][e] in bf16, [256 x 1792] -------
__global__ __launch_bounds__(256) void k_prep(
    const float* __restrict__ wself,
    const float* __restrict__ w0, const float* __restrict__ w1,
    const float* __restrict__ w2, const float* __restrict__ w3,
    const float* __restrict__ w4, const float* __restrict__ w5,
    u16* __restrict__ wcatT){
  int e = blockIdx.x;
  const float* Ws[7] = {wself, w0, w1, w2, w3, w4, w5};
  for (int c = threadIdx.x; c < KC; c += 256){
    int g = c >> 8, j = c & 255;
    wcatT[(size_t)e*KC + c] = f2bf(Ws[g][j*Dd + e]);
  }
}

// ---------------- K0b: pack node_mask into bit-words, Mp[b][w] ------------
__global__ __launch_bounds__(512) void k_mask(
    const int* __restrict__ mask, unsigned* __restrict__ Mp){
  int t = threadIdx.x;                 // 512 = 32 batches x 16 words
  int b = t >> 4, w = t & 15;
  const int4* mp = (const int4*)(mask + (size_t)b * Nn + w * 32);
  unsigned v = 0;
  #pragma unroll
  for (int j = 0; j < 8; ++j){
    int4 x = mp[j];
    v |= ((unsigned)x.x << (j * 4)) | ((unsigned)x.y << (j * 4 + 1)) |
         ((unsigned)x.z << (j * 4 + 2)) | ((unsigned)x.w << (j * 4 + 3));
  }
  Mp[t] = v;
}

// ---------------- K1: bitpack graphs + nn popcount (streaming, no LDS) -----
// One thread = one word (row r, cols 32w..32w+31), all 6 graphs:
// 48 independent int4 loads, pure bit-op packing, popc + 16-lane reduce.
// Gp[k][b][m][w]: bit j of word w = masked G value at col 32w+j (unchanged).
__global__ __launch_bounds__(256) void k_pack(
    const int* __restrict__ g0, const int* __restrict__ g1,
    const int* __restrict__ g2, const int* __restrict__ g3,
    const int* __restrict__ g4, const int* __restrict__ g5,
    const int* __restrict__ mask, const unsigned* __restrict__ Mp,
    unsigned* __restrict__ Gp, float* __restrict__ rs){
  int t = blockIdx.x * 256 + threadIdx.x;
  int w = t & 15, r = t >> 4;           // r = b*512 + m
  int b = r >> 9, m = r & 511;
  unsigned keep = Mp[b * 16 + w] & ~(((m >> 5) == w) ? (1u << (m & 31)) : 0u);
  const int* gs[6] = {g0, g1, g2, g3, g4, g5};
  int stot = 0;
  #pragma unroll
  for (int k = 0; k < 6; ++k){
    const int4* gp = (const int4*)(gs[k] + (size_t)r * Nn + w * 32);
    unsigned v = 0;
    #pragma unroll
    for (int j = 0; j < 8; ++j){
      int4 x = gp[j];
      v |= ((unsigned)x.x << (j * 4)) | ((unsigned)x.y << (j * 4 + 1)) |
           ((unsigned)x.z << (j * 4 + 2)) | ((unsigned)x.w << (j * 4 + 3));
    }
    v &= keep;
    stot += __popc(v);
    Gp[((size_t)k * Bb * Nn + r) * 16 + w] = v;
  }
  stot += __shfl_xor(stot, 1);
  stot += __shfl_xor(stot, 2);
  stot += __shfl_xor(stot, 4);
  stot += __shfl_xor(stot, 8);
  if (w == 0)
    rs[r] = mask[r] ? 1.0f / (float)(stot < 1 ? 1 : stot) : 0.0f;
}

// ---------------- K2: dw (sigmoid), Z node copy (bf16), X'^T build ---------
__global__ __launch_bounds__(256) void k_dw(
    const float* __restrict__ node, const int* __restrict__ mask,
    const float* __restrict__ wnw, const float* __restrict__ bnw,
    float* __restrict__ aw_out,    // already offset by t*N
    u16* __restrict__ Z, u16* __restrict__ XT){
  __shared__ float tile[32][268];
  __shared__ float dws[32];
  int b = blockIdx.x >> 4, n0 = (blockIdx.x & 15) << 5;
  int t = threadIdx.x;
  int row = t >> 3, seg = t & 7;
  const float* src = node + ((size_t)(b * Nn + n0 + row)) * Dd + seg * 32;
  u16* zn = Z + ((size_t)(b * Nn + n0 + row)) * KC + seg * 32;
  #pragma unroll
  for (int c = 0; c < 8; ++c){
    float4 v = ((const float4*)src)[c];
    tile[row][seg * 32 + c * 4 + 0] = v.x;
    tile[row][seg * 32 + c * 4 + 1] = v.y;
    tile[row][seg * 32 + c * 4 + 2] = v.z;
    tile[row][seg * 32 + c * 4 + 3] = v.w;
    ushort4 h;
    h.x = f2bf(v.x); h.y = f2bf(v.y); h.z = f2bf(v.z); h.w = f2bf(v.w);
    ((ushort4*)zn)[c] = h;
  }
  __syncthreads();
  float s = 0.f;
  #pragma unroll
  for (int c = 0; c < 32; ++c) s += tile[row][seg * 32 + c] * wnw[seg * 32 + c];
  s += __shfl_xor(s, 1); s += __shfl_xor(s, 2); s += __shfl_xor(s, 4);
  if (seg == 0){
    float dw = 1.f / (1.f + expf(-(s + bnw[0])));
    aw_out[b * (2 * Nn) + n0 + row] = dw;
    dws[row] = mask[b * Nn + n0 + row] ? dw : 0.f;
  }
  __syncthreads();
  #pragma unroll
  for (int p = 0; p < 4; ++p){
    int d = p * 64 + (t >> 2);
    int j0 = (t & 3) * 8;
    union { u16 h[8]; uint4 v; } pk;
    #pragma unroll
    for (int jj = 0; jj < 8; ++jj)
      pk.h[jj] = f2bf(dws[j0 + jj] * tile[j0 + jj][d]);
    *(uint4*)(XT + ((size_t)(b * Dd + d)) * Nn + n0 + j0) = pk.v;
  }
}

// ---------------- K3: aggregation GEMM  H'_k = rs * (G_k @ X') ------------
// grid (8, 32, 6): mtile, b, edge-type.  BM=64, BN=256(full D), BK=64, 4 waves
__global__ __launch_bounds__(256) void k_agg(
    const unsigned* __restrict__ Gp,
    const u16* __restrict__ XT, const float* __restrict__ rs,
    u16* __restrict__ Z){
  int mt = blockIdx.x, b = blockIdx.y, kg = blockIdx.z;
  int m0 = mt * 64;
  const unsigned* Gr = Gp + ((size_t)kg * Bb * Nn + b * Nn + m0) * 16;
  const u16* Xb = XT + (size_t)b * Dd * Nn;
  __shared__ u16 As[64 * 72];
  __shared__ u16 Bs[256 * 72];
  int t = threadIdx.x, lane = t & 63, wn = t >> 6;
  int arow = t >> 2, aq = t & 3;
  // preload this thread's 8 packed words (one per K-step), L2-hit
  unsigned wpre[8];
  #pragma unroll
  for (int ks = 0; ks < 8; ++ks)
    wpre[ks] = Gr[arow * 16 + ks * 2 + (aq >> 1)];

  f32x4 acc[4][4];
  #pragma unroll
  for (int i = 0; i < 4; ++i)
    #pragma unroll
    for (int q = 0; q < 4; ++q) acc[i][q] = (f32x4){0.f, 0.f, 0.f, 0.f};

  for (int ks = 0; ks < 8; ++ks){
    int k0 = ks * 64;
    { // A stage: unpack 16 bits -> bf16 0/1
      unsigned bits = (wpre[ks] >> ((aq & 1) * 16)) & 0xFFFFu;
      union { u16 h[16]; uint4 v[2]; } pk;
      #pragma unroll
      for (int c = 0; c < 16; ++c)
        pk.h[c] = ((bits >> c) & 1u) ? 0x3F80 : 0;
      *(uint4*)&As[arow * 72 + aq * 16]     = pk.v[0];
      *(uint4*)&As[arow * 72 + aq * 16 + 8] = pk.v[1];
    }
    // B stage: 256 rows (d) x 64 cols (n-slice) from X'^T
    #pragma unroll
    for (int p = 0; p < 8; ++p){
      int rowb = p * 32 + (t >> 3);
      *(uint4*)&Bs[rowb * 72 + (t & 7) * 8] =
          *(const uint4*)(Xb + (size_t)rowb * Nn + k0 + (t & 7) * 8);
    }
    __syncthreads();
    #pragma unroll
    for (int kk = 0; kk < 2; ++kk){
      bf16x8 av[4], bv[4];
      #pragma unroll
      for (int i = 0; i < 4; ++i)
        av[i] = *(const bf16x8*)&As[(i * 16 + (lane & 15)) * 72 + kk * 32 + (lane >> 4) * 8];
      #pragma unroll
      for (int q = 0; q < 4; ++q)
        bv[q] = *(const bf16x8*)&Bs[(wn * 64 + q * 16 + (lane & 15)) * 72 + kk * 32 + (lane >> 4) * 8];
      #pragma unroll
      for (int i = 0; i < 4; ++i)
        #pragma unroll
        for (int q = 0; q < 4; ++q)
          acc[i][q] = __builtin_amdgcn_mfma_f32_16x16x32_bf16(av[i], bv[q], acc[i][q], 0, 0, 0);
    }
    __syncthreads();
  }
  int kgcol = 256 + kg * 256 + wn * 64;
  #pragma unroll
  for (int i = 0; i < 4; ++i){
    #pragma unroll
    for (int r = 0; r < 4; ++r){
      int mg = m0 + i * 16 + (lane >> 4) * 4 + r;
      float sc = rs[b * Nn + mg];
      u16* zp = Z + ((size_t)(b * Nn + mg)) * KC + kgcol + (lane & 15);
      #pragma unroll
      for (int q = 0; q < 4; ++q)
        zp[q * 16] = f2bf(acc[i][q][r] * sc);
    }
  }
}

// ---------------- K4: update GEMM  out = relu(Z @ Wcat + b_self) ----------
// grid (2, 128): ntile, mtile. BM=128, BN=128, BK=64, 4 waves (2x2)
__global__ __launch_bounds__(256) void k_upd(
    const u16* __restrict__ Z, const u16* __restrict__ wcatT,
    const float* __restrict__ bself, float* __restrict__ outp){
  int n0 = blockIdx.x * 128, m0 = blockIdx.y * 128;
  __shared__ u16 As[128 * 72];
  __shared__ u16 Bs[128 * 72];
  int t = threadIdx.x, lane = t & 63, wid = t >> 6;
  int wm = wid >> 1, wn = wid & 1;
  f32x4 acc[4][4];
  #pragma unroll
  for (int i = 0; i < 4; ++i)
    #pragma unroll
    for (int q = 0; q < 4; ++q) acc[i][q] = (f32x4){0.f, 0.f, 0.f, 0.f};

  for (int ks = 0; ks < 28; ++ks){
    int k0 = ks * 64;
    #pragma unroll
    for (int p = 0; p < 4; ++p){
      int row = p * 32 + (t >> 3);
      *(uint4*)&As[row * 72 + (t & 7) * 8] =
          *(const uint4*)(Z + ((size_t)(m0 + row)) * KC + k0 + (t & 7) * 8);
      *(uint4*)&Bs[row * 72 + (t & 7) * 8] =
          *(const uint4*)(wcatT + ((size_t)(n0 + row)) * KC + k0 + (t & 7) * 8);
    }
    __syncthreads();
    #pragma unroll
    for (int kk = 0; kk < 2; ++kk){
      bf16x8 av[4], bv[4];
      #pragma unroll
      for (int i = 0; i < 4; ++i)
        av[i] = *(const bf16x8*)&As[(wm * 64 + i * 16 + (lane & 15)) * 72 + kk * 32 + (lane >> 4) * 8];
      #pragma unroll
      for (int q = 0; q < 4; ++q)
        bv[q] = *(const bf16x8*)&Bs[(wn * 64 + q * 16 + (lane & 15)) * 72 + kk * 32 + (lane >> 4) * 8];
      #pragma unroll
      for (int i = 0; i < 4; ++i)
        #pragma unroll
        for (int q = 0; q < 4; ++q)
          acc[i][q] = __builtin_amdgcn_mfma_f32_16x16x32_bf16(av[i], bv[q], acc[i][q], 0, 0, 0);
    }
    __syncthreads();
  }
  #pragma unroll
  for (int i = 0; i < 4; ++i){
    #pragma unroll
    for (int r = 0; r < 4; ++r){
      int mg = m0 + wm * 64 + i * 16 + (lane >> 4) * 4 + r;
      #pragma unroll
      for (int q = 0; q < 4; ++q){
        int e = n0 + wn * 64 + q * 16 + (lane & 15);
        float v = acc[i][q][r] + bself[e];
        outp[(size_t)mg * Dd + e] = v > 0.f ? v : 0.f;
      }
    }
  }
}

extern "C" void kernel_launch(void* const* d_in, const int* in_sizes, int n_in,
                              void* d_out, int out_size, void* d_ws, size_t ws_size,
                              hipStream_t stream){
  (void)in_sizes; (void)n_in; (void)out_size; (void)ws_size;
  const float* node  = (const float*)d_in[0];
  const int*   mask  = (const int*)d_in[1];
  const int*   g[6];
  for (int i = 0; i < 6; ++i) g[i] = (const int*)d_in[2 + i];
  const float* wnw   = (const float*)d_in[8];
  const float* bnw   = (const float*)d_in[9];
  const float* wself = (const float*)d_in[10];
  const float* bself = (const float*)d_in[11];
  const float* W[6];
  for (int i = 0; i < 6; ++i) W[i] = (const float*)d_in[12 + i];

  float* out_node = (float*)d_out;
  float* out_aw   = out_node + (size_t)Bb * Nn * Dd;

  char* ws = (char*)d_ws;
  u16*      wcatT = (u16*)(ws);                    // 917,504 B
  float*    rs    = (float*)(ws + 917504);         // 65,536 B
  unsigned* Mp    = (unsigned*)(ws + 983040);      // 2,048 B
  unsigned* Gp    = (unsigned*)(ws + 1048576);     // 6,291,456 B
  u16*      XT    = (u16*)(ws + 7340032);          // 8,388,608 B
  u16*      Z     = (u16*)(ws + 15728640);         // 58,720,256 B -> ends ~71 MB

  k_prep<<<256, 256, 0, stream>>>(wself, W[0], W[1], W[2], W[3], W[4], W[5], wcatT);
  k_mask<<<1, 512, 0, stream>>>(mask, Mp);
  k_pack<<<1024, 256, 0, stream>>>(g[0], g[1], g[2], g[3], g[4], g[5], mask, Mp, Gp, rs);

  for (int t = 0; t < 2; ++t){
    const float* nsrc = (t == 0) ? node : out_node;   // iter-1 result lives in d_out
    k_dw<<<512, 256, 0, stream>>>(nsrc, mask, wnw, bnw, out_aw + t * Nn, Z, XT);
    k_agg<<<dim3(8, 32, 6), 256, 0, stream>>>(Gp, XT, rs, Z);
    k_upd<<<dim3(2, 128), 256, 0, stream>>>(Z, wcatT, bself, out_node);
  }
}

// Round 7
// 254.026 us; speedup vs baseline: 1.0363x; 1.0363x over previous
//
#include <hip/hip_runtime.h>

#define Bb 32
#define Nn 512
#define Dd 256
#define KC 1792   // 256 (self) + 6*256 (edge types)

typedef __bf16 bf16x8 __attribute__((ext_vector_type(8)));
typedef float  f32x4  __attribute__((ext_vector_type(4)));
typedef unsigned short u16;

typedef const __attribute__((address_space(1))) void cgv_t;
typedef __attribute__((address_space(3))) void lv_t;

__device__ __forceinline__ u16 f2bf(float x){
  union { float f; unsigned u; } c; c.f = x;
  unsigned u = c.u;
  u += 0x7FFFu + ((u >> 16) & 1u);   // RNE
  return (u16)(u >> 16);
}

// ---------------- K0: WcatT[e][c] = Wcat[c][e] in bf16, [256 x 1792] -------
__global__ __launch_bounds__(256) void k_prep(
    const float* __restrict__ wself,
    const float* __restrict__ w0, const float* __restrict__ w1,
    const float* __restrict__ w2, const float* __restrict__ w3,
    const float* __restrict__ w4, const float* __restrict__ w5,
    u16* __restrict__ wcatT){
  int e = blockIdx.x;
  const float* Ws[7] = {wself, w0, w1, w2, w3, w4, w5};
  for (int c = threadIdx.x; c < KC; c += 256){
    int g = c >> 8, j = c & 255;
    wcatT[(size_t)e*KC + c] = f2bf(Ws[g][j*Dd + e]);
  }
}

// ---------------- K0b: pack node_mask into bit-words, Mp[b][w] ------------
__global__ __launch_bounds__(512) void k_mask(
    const int* __restrict__ mask, unsigned* __restrict__ Mp){
  int t = threadIdx.x;                 // 512 = 32 batches x 16 words
  int b = t >> 4, w = t & 15;
  const int4* mp = (const int4*)(mask + (size_t)b * Nn + w * 32);
  unsigned v = 0;
  #pragma unroll
  for (int j = 0; j < 8; ++j){
    int4 x = mp[j];
    v |= ((unsigned)x.x << (j * 4)) | ((unsigned)x.y << (j * 4 + 1)) |
         ((unsigned)x.z << (j * 4 + 2)) | ((unsigned)x.w << (j * 4 + 3));
  }
  Mp[t] = v;
}

// ---------------- K1: bitpack graphs + nn (global_load_lds pipeline) -------
// Block = 16 rows. Per row: 6 graph-rows (12 KB) staged to LDS via 12
// wave-uniform global_load_lds(16B) chunks; double-buffered, raw barriers,
// counted vmcnt(3) so next-row loads stay in flight. Consume: 96 thr x
// 8 ds_read_b128 -> bit-pack -> Gp; popc + shfl reduce -> rs.
// Gp[k][b][m][w]: bit j of word w = masked G value at col 32w+j (unchanged).
__device__ __forceinline__ void gl16(const int* src, int* dst){
  __builtin_amdgcn_global_load_lds((cgv_t*)src, (lv_t*)dst, 16, 0, 0);
}

__global__ __launch_bounds__(256) void k_pack(
    const int* __restrict__ g0, const int* __restrict__ g1,
    const int* __restrict__ g2, const int* __restrict__ g3,
    const int* __restrict__ g4, const int* __restrict__ g5,
    const int* __restrict__ mask, const unsigned* __restrict__ Mp,
    unsigned* __restrict__ Gp, float* __restrict__ rs){
  __shared__ int buf[2][3072];        // [6 graphs][512 ints] per buffer
  __shared__ int red[2];
  int t = threadIdx.x, lane = t & 63, wv = t >> 6;
  int R = blockIdx.x * 16, b = R >> 9;

  // staging chunks owned by this wave: c = wv*3 + j  (chunk c: graph c>>1,
  // half c&1; 1KB per chunk, wave-uniform LDS base, per-lane global src)
  int c0 = wv * 3, c1 = c0 + 1, c2 = c0 + 2;
  const int* p0 = g0;                  // branchless graph select (no arrays)
  const int* p1 = g0; const int* p2 = g0;
  {
    int k0 = c0 >> 1, k1 = c1 >> 1, k2 = c2 >> 1;
    p0 = (k0==1)?g1:p0; p0 = (k0==2)?g2:p0; p0 = (k0==3)?g3:p0; p0 = (k0==4)?g4:p0; p0 = (k0==5)?g5:p0;
    p1 = (k1==1)?g1:p1; p1 = (k1==2)?g2:p1; p1 = (k1==3)?g3:p1; p1 = (k1==4)?g4:p1; p1 = (k1==5)?g5:p1;
    p2 = (k2==1)?g1:p2; p2 = (k2==2)?g2:p2; p2 = (k2==3)?g3:p2; p2 = (k2==4)?g4:p2; p2 = (k2==5)?g5:p2;
  }
  const int* s0 = p0 + (size_t)R * Nn + (c0 & 1) * 256 + lane * 4;
  const int* s1 = p1 + (size_t)R * Nn + (c1 & 1) * 256 + lane * 4;
  const int* s2 = p2 + (size_t)R * Nn + (c2 & 1) * 256 + lane * 4;
  int* d0[2] = {&buf[0][c0 * 256], &buf[1][c0 * 256]};
  int* d1[2] = {&buf[0][c1 * 256], &buf[1][c1 * 256]};
  int* d2[2] = {&buf[0][c2 * 256], &buf[1][c2 * 256]};

  int kk = t >> 4, ww = t & 15;        // consume role (threads 0..95)
  unsigned keepw = (t < 96) ? Mp[b * 16 + ww] : 0u;

#define STAGE(B) { gl16(s0, d0[B]); gl16(s1, d1[B]); gl16(s2, d2[B]); \
                   s0 += Nn; s1 += Nn; s2 += Nn; }

  auto consume = [&](const int* cb, int r){
    if (t < 96){
      int m = r & 511;
      unsigned keep = keepw & ~(((m >> 5) == ww) ? (1u << (m & 31)) : 0u);
      const int4* p = (const int4*)(cb + kk * 512 + ww * 32);
      unsigned v = 0;
      #pragma unroll
      for (int j = 0; j < 8; ++j){
        int4 x = p[j];
        v |= ((unsigned)x.x << (j * 4)) | ((unsigned)x.y << (j * 4 + 1)) |
             ((unsigned)x.z << (j * 4 + 2)) | ((unsigned)x.w << (j * 4 + 3));
      }
      v &= keep;
      Gp[((size_t)kk * (Bb * Nn) + r) * 16 + ww] = v;
      int s = __popc(v);
      s += __shfl_xor(s, 1); s += __shfl_xor(s, 2); s += __shfl_xor(s, 4);
      s += __shfl_xor(s, 8); s += __shfl_xor(s, 16);
      if (wv == 0) s += __shfl_xor(s, 32);   // wave1 has only 32 active lanes
      if (lane == 0) red[wv] = s;
    }
  };
  auto rs_row = [&](int r){
    if (t == 0){
      int s = red[0] + red[1];
      rs[r] = mask[r] ? 1.0f / (float)(s < 1 ? 1 : s) : 0.0f;
    }
  };

  STAGE(0); STAGE(1);                  // rows R, R+1 in flight
  for (int p = 0; p < 8; ++p){
    int r0 = R + 2 * p, r1 = r0 + 1;
    // ---- consume buf0 (row r0); buf1's 3 loads stay outstanding ----
    asm volatile("s_waitcnt vmcnt(3)" ::: "memory");
    __builtin_amdgcn_s_barrier();
    __builtin_amdgcn_sched_barrier(0);
    consume(buf[0], r0);
    __builtin_amdgcn_s_barrier();
    rs_row(r0);
    if (p < 7) STAGE(0);               // row r0+2 -> buf0
    // ---- consume buf1 (row r1) ----
    if (p < 7) { asm volatile("s_waitcnt vmcnt(3)" ::: "memory"); }
    else       { asm volatile("s_waitcnt vmcnt(0)" ::: "memory"); }
    __builtin_amdgcn_s_barrier();
    __builtin_amdgcn_sched_barrier(0);
    consume(buf[1], r1);
    __builtin_amdgcn_s_barrier();
    rs_row(r1);
    if (p < 7) STAGE(1);               // row r1+2 -> buf1
  }
#undef STAGE
}

// ---------------- K2: dw (sigmoid), Z node copy (bf16), X'^T build ---------
__global__ __launch_bounds__(256) void k_dw(
    const float* __restrict__ node, const int* __restrict__ mask,
    const float* __restrict__ wnw, const float* __restrict__ bnw,
    float* __restrict__ aw_out,    // already offset by t*N
    u16* __restrict__ Z, u16* __restrict__ XT){
  __shared__ float tile[32][268];
  __shared__ float dws[32];
  int b = blockIdx.x >> 4, n0 = (blockIdx.x & 15) << 5;
  int t = threadIdx.x;
  int row = t >> 3, seg = t & 7;
  const float* src = node + ((size_t)(b * Nn + n0 + row)) * Dd + seg * 32;
  u16* zn = Z + ((size_t)(b * Nn + n0 + row)) * KC + seg * 32;
  #pragma unroll
  for (int c = 0; c < 8; ++c){
    float4 v = ((const float4*)src)[c];
    tile[row][seg * 32 + c * 4 + 0] = v.x;
    tile[row][seg * 32 + c * 4 + 1] = v.y;
    tile[row][seg * 32 + c * 4 + 2] = v.z;
    tile[row][seg * 32 + c * 4 + 3] = v.w;
    ushort4 h;
    h.x = f2bf(v.x); h.y = f2bf(v.y); h.z = f2bf(v.z); h.w = f2bf(v.w);
    ((ushort4*)zn)[c] = h;
  }
  __syncthreads();
  float s = 0.f;
  #pragma unroll
  for (int c = 0; c < 32; ++c) s += tile[row][seg * 32 + c] * wnw[seg * 32 + c];
  s += __shfl_xor(s, 1); s += __shfl_xor(s, 2); s += __shfl_xor(s, 4);
  if (seg == 0){
    float dw = 1.f / (1.f + expf(-(s + bnw[0])));
    aw_out[b * (2 * Nn) + n0 + row] = dw;
    dws[row] = mask[b * Nn + n0 + row] ? dw : 0.f;
  }
  __syncthreads();
  #pragma unroll
  for (int p = 0; p < 4; ++p){
    int d = p * 64 + (t >> 2);
    int j0 = (t & 3) * 8;
    union { u16 h[8]; uint4 v; } pk;
    #pragma unroll
    for (int jj = 0; jj < 8; ++jj)
      pk.h[jj] = f2bf(dws[j0 + jj] * tile[j0 + jj][d]);
    *(uint4*)(XT + ((size_t)(b * Dd + d)) * Nn + n0 + j0) = pk.v;
  }
}

// ---------------- K3: aggregation GEMM  H'_k = rs * (G_k @ X') ------------
// grid (8, 32, 6): mtile, b, edge-type.  BM=64, BN=256(full D), BK=64, 4 waves
__global__ __launch_bounds__(256) void k_agg(
    const unsigned* __restrict__ Gp,
    const u16* __restrict__ XT, const float* __restrict__ rs,
    u16* __restrict__ Z){
  int mt = blockIdx.x, b = blockIdx.y, kg = blockIdx.z;
  int m0 = mt * 64;
  const unsigned* Gr = Gp + ((size_t)kg * Bb * Nn + b * Nn + m0) * 16;
  const u16* Xb = XT + (size_t)b * Dd * Nn;
  __shared__ u16 As[64 * 72];
  __shared__ u16 Bs[256 * 72];
  int t = threadIdx.x, lane = t & 63, wn = t >> 6;
  int arow = t >> 2, aq = t & 3;
  // preload this thread's 8 packed words (one per K-step), L2-hit
  unsigned wpre[8];
  #pragma unroll
  for (int ks = 0; ks < 8; ++ks)
    wpre[ks] = Gr[arow * 16 + ks * 2 + (aq >> 1)];

  f32x4 acc[4][4];
  #pragma unroll
  for (int i = 0; i < 4; ++i)
    #pragma unroll
    for (int q = 0; q < 4; ++q) acc[i][q] = (f32x4){0.f, 0.f, 0.f, 0.f};

  for (int ks = 0; ks < 8; ++ks){
    int k0 = ks * 64;
    { // A stage: unpack 16 bits -> bf16 0/1
      unsigned bits = (wpre[ks] >> ((aq & 1) * 16)) & 0xFFFFu;
      union { u16 h[16]; uint4 v[2]; } pk;
      #pragma unroll
      for (int c = 0; c < 16; ++c)
        pk.h[c] = ((bits >> c) & 1u) ? 0x3F80 : 0;
      *(uint4*)&As[arow * 72 + aq * 16]     = pk.v[0];
      *(uint4*)&As[arow * 72 + aq * 16 + 8] = pk.v[1];
    }
    // B stage: 256 rows (d) x 64 cols (n-slice) from X'^T
    #pragma unroll
    for (int p = 0; p < 8; ++p){
      int rowb = p * 32 + (t >> 3);
      *(uint4*)&Bs[rowb * 72 + (t & 7) * 8] =
          *(const uint4*)(Xb + (size_t)rowb * Nn + k0 + (t & 7) * 8);
    }
    __syncthreads();
    #pragma unroll
    for (int kk = 0; kk < 2; ++kk){
      bf16x8 av[4], bv[4];
      #pragma unroll
      for (int i = 0; i < 4; ++i)
        av[i] = *(const bf16x8*)&As[(i * 16 + (lane & 15)) * 72 + kk * 32 + (lane >> 4) * 8];
      #pragma unroll
      for (int q = 0; q < 4; ++q)
        bv[q] = *(const bf16x8*)&Bs[(wn * 64 + q * 16 + (lane & 15)) * 72 + kk * 32 + (lane >> 4) * 8];
      #pragma unroll
      for (int i = 0; i < 4; ++i)
        #pragma unroll
        for (int q = 0; q < 4; ++q)
          acc[i][q] = __builtin_amdgcn_mfma_f32_16x16x32_bf16(av[i], bv[q], acc[i][q], 0, 0, 0);
    }
    __syncthreads();
  }
  int kgcol = 256 + kg * 256 + wn * 64;
  #pragma unroll
  for (int i = 0; i < 4; ++i){
    #pragma unroll
    for (int r = 0; r < 4; ++r){
      int mg = m0 + i * 16 + (lane >> 4) * 4 + r;
      float sc = rs[b * Nn + mg];
      u16* zp = Z + ((size_t)(b * Nn + mg)) * KC + kgcol + (lane & 15);
      #pragma unroll
      for (int q = 0; q < 4; ++q)
        zp[q * 16] = f2bf(acc[i][q][r] * sc);
    }
  }
}

// ---------------- K4: update GEMM  out = relu(Z @ Wcat + b_self) ----------
// grid (2, 128): ntile, mtile. BM=128, BN=128, BK=64, 4 waves (2x2)
__global__ __launch_bounds__(256) void k_upd(
    const u16* __restrict__ Z, const u16* __restrict__ wcatT,
    const float* __restrict__ bself, float* __restrict__ outp){
  int n0 = blockIdx.x * 128, m0 = blockIdx.y * 128;
  __shared__ u16 As[128 * 72];
  __shared__ u16 Bs[128 * 72];
  int t = threadIdx.x, lane = t & 63, wid = t >> 6;
  int wm = wid >> 1, wn = wid & 1;
  f32x4 acc[4][4];
  #pragma unroll
  for (int i = 0; i < 4; ++i)
    #pragma unroll
    for (int q = 0; q < 4; ++q) acc[i][q] = (f32x4){0.f, 0.f, 0.f, 0.f};

  for (int ks = 0; ks < 28; ++ks){
    int k0 = ks * 64;
    #pragma unroll
    for (int p = 0; p < 4; ++p){
      int row = p * 32 + (t >> 3);
      *(uint4*)&As[row * 72 + (t & 7) * 8] =
          *(const uint4*)(Z + ((size_t)(m0 + row)) * KC + k0 + (t & 7) * 8);
      *(uint4*)&Bs[row * 72 + (t & 7) * 8] =
          *(const uint4*)(wcatT + ((size_t)(n0 + row)) * KC + k0 + (t & 7) * 8);
    }
    __syncthreads();
    #pragma unroll
    for (int kk = 0; kk < 2; ++kk){
      bf16x8 av[4], bv[4];
      #pragma unroll
      for (int i = 0; i < 4; ++i)
        av[i] = *(const bf16x8*)&As[(wm * 64 + i * 16 + (lane & 15)) * 72 + kk * 32 + (lane >> 4) * 8];
      #pragma unroll
      for (int q = 0; q < 4; ++q)
        bv[q] = *(const bf16x8*)&Bs[(wn * 64 + q * 16 + (lane & 15)) * 72 + kk * 32 + (lane >> 4) * 8];
      #pragma unroll
      for (int i = 0; i < 4; ++i)
        #pragma unroll
        for (int q = 0; q < 4; ++q)
          acc[i][q] = __builtin_amdgcn_mfma_f32_16x16x32_bf16(av[i], bv[q], acc[i][q], 0, 0, 0);
    }
    __syncthreads();
  }
  #pragma unroll
  for (int i = 0; i < 4; ++i){
    #pragma unroll
    for (int r = 0; r < 4; ++r){
      int mg = m0 + wm * 64 + i * 16 + (lane >> 4) * 4 + r;
      #pragma unroll
      for (int q = 0; q < 4; ++q){
        int e = n0 + wn * 64 + q * 16 + (lane & 15);
        float v = acc[i][q][r] + bself[e];
        outp[(size_t)mg * Dd + e] = v > 0.f ? v : 0.f;
      }
    }
  }
}

extern "C" void kernel_launch(void* const* d_in, const int* in_sizes, int n_in,
                              void* d_out, int out_size, void* d_ws, size_t ws_size,
                              hipStream_t stream){
  (void)in_sizes; (void)n_in; (void)out_size; (void)ws_size;
  const float* node  = (const float*)d_in[0];
  const int*   mask  = (const int*)d_in[1];
  const int*   g[6];
  for (int i = 0; i < 6; ++i) g[i] = (const int*)d_in[2 + i];
  const float* wnw   = (const float*)d_in[8];
  const float* bnw   = (const float*)d_in[9];
  const float* wself = (const float*)d_in[10];
  const float* bself = (const float*)d_in[11];
  const float* W[6];
  for (int i = 0; i < 6; ++i) W[i] = (const float*)d_in[12 + i];

  float* out_node = (float*)d_out;
  float* out_aw   = out_node + (size_t)Bb * Nn * Dd;

  char* ws = (char*)d_ws;
  u16*      wcatT = (u16*)(ws);                    // 917,504 B
  float*    rs    = (float*)(ws + 917504);         // 65,536 B
  unsigned* Mp    = (unsigned*)(ws + 983040);      // 2,048 B
  unsigned* Gp    = (unsigned*)(ws + 1048576);     // 6,291,456 B
  u16*      XT    = (u16*)(ws + 7340032);          // 8,388,608 B
  u16*      Z     = (u16*)(ws + 15728640);         // 58,720,256 B -> ends ~71 MB

  k_prep<<<256, 256, 0, stream>>>(wself, W[0], W[1], W[2], W[3], W[4], W[5], wcatT);
  k_mask<<<1, 512, 0, stream>>>(mask, Mp);
  k_pack<<<1024, 256, 0, stream>>>(g[0], g[1], g[2], g[3], g[4], g[5], mask, Mp, Gp, rs);

  for (int t = 0; t < 2; ++t){
    const float* nsrc = (t == 0) ? node : out_node;   // iter-1 result lives in d_out
    k_dw<<<512, 256, 0, stream>>>(nsrc, mask, wnw, bnw, out_aw + t * Nn, Z, XT);
    k_agg<<<dim3(8, 32, 6), 256, 0, stream>>>(Gp, XT, rs, Z);
    k_upd<<<dim3(2, 128), 256, 0, stream>>>(Z, wcatT, bself, out_node);
  }
}

// Round 8
// 249.421 us; speedup vs baseline: 1.0554x; 1.0185x over previous
//
#include <hip/hip_runtime.h>

#define Bb 32
#define Nn 512
#define Dd 256
#define KC 1792   // 256 (self) + 6*256 (edge types)

typedef __bf16 bf16x8 __attribute__((ext_vector_type(8)));
typedef float  f32x4  __attribute__((ext_vector_type(4)));
typedef int    i32x4  __attribute__((ext_vector_type(4)));
typedef unsigned short u16;

__device__ __forceinline__ u16 f2bf(float x){
  union { float f; unsigned u; } c; c.f = x;
  unsigned u = c.u;
  u += 0x7FFFu + ((u >> 16) & 1u);   // RNE
  return (u16)(u >> 16);
}

// ---------------- K0: WcatT[e][c] = Wcat[c][e] in bf16, [256 x 1792] -------
__global__ __launch_bounds__(256) void k_prep(
    const float* __restrict__ wself,
    const float* __restrict__ w0, const float* __restrict__ w1,
    const float* __restrict__ w2, const float* __restrict__ w3,
    const float* __restrict__ w4, const float* __restrict__ w5,
    u16* __restrict__ wcatT){
  int e = blockIdx.x;
  const float* Ws[7] = {wself, w0, w1, w2, w3, w4, w5};
  for (int c = threadIdx.x; c < KC; c += 256){
    int g = c >> 8, j = c & 255;
    wcatT[(size_t)e*KC + c] = f2bf(Ws[g][j*Dd + e]);
  }
}

// ---------------- K0b: pack node_mask into bit-words, Mp[b][w] ------------
__global__ __launch_bounds__(512) void k_mask(
    const int* __restrict__ mask, unsigned* __restrict__ Mp){
  int t = threadIdx.x;                 // 512 = 32 batches x 16 words
  int b = t >> 4, w = t & 15;
  const int4* mp = (const int4*)(mask + (size_t)b * Nn + w * 32);
  unsigned v = 0;
  #pragma unroll
  for (int j = 0; j < 8; ++j){
    int4 x = mp[j];
    v |= ((unsigned)x.x << (j * 4)) | ((unsigned)x.y << (j * 4 + 1)) |
         ((unsigned)x.z << (j * 4 + 2)) | ((unsigned)x.w << (j * 4 + 3));
  }
  Mp[t] = v;
}

// ---------------- K1: bitpack graphs + nn (asm-forced MLP streaming) -------
// One thread = one word (row r, cols 32w..32w+31), all 6 graphs.
// Loads via inline-asm global_load_dwordx4 in 2 batches of 24 (3 graphs),
// each drained by ONE s_waitcnt vmcnt(0): 24 loads in flight per wave,
// guaranteed. No LDS, no barriers, no ballots.
// Gp[k][b][m][w]: bit j of word w = masked G value at col 32w+j (unchanged).
#define GLD(d, p, o) asm volatile("global_load_dwordx4 %0, %1, off offset:" #o \
                                  : "=v"(d) : "v"(p))
#define GLD8(a, p) GLD(a[0], p, 0);  GLD(a[1], p, 16); GLD(a[2], p, 32); \
                   GLD(a[3], p, 48); GLD(a[4], p, 64); GLD(a[5], p, 80); \
                   GLD(a[6], p, 96); GLD(a[7], p, 112)

__device__ __forceinline__ unsigned packw(const i32x4* x){
  unsigned v = 0;
  #pragma unroll
  for (int j = 0; j < 8; ++j){
    v |= ((unsigned)x[j][0] << (4 * j))     | ((unsigned)x[j][1] << (4 * j + 1)) |
         ((unsigned)x[j][2] << (4 * j + 2)) | ((unsigned)x[j][3] << (4 * j + 3));
  }
  return v;
}

__global__ __launch_bounds__(256) void k_pack(
    const int* __restrict__ g0, const int* __restrict__ g1,
    const int* __restrict__ g2, const int* __restrict__ g3,
    const int* __restrict__ g4, const int* __restrict__ g5,
    const int* __restrict__ mask, const unsigned* __restrict__ Mp,
    unsigned* __restrict__ Gp, float* __restrict__ rs){
  int t = blockIdx.x * 256 + threadIdx.x;
  int w = t & 15, r = t >> 4;           // r = b*512 + m
  int b = r >> 9, m = r & 511;
  unsigned keep = Mp[b * 16 + w] & ~(((m >> 5) == w) ? (1u << (m & 31)) : 0u);
  size_t off = (size_t)r * Nn + w * 32;
  const int* pa = g0 + off;  const int* pb = g1 + off;  const int* pc = g2 + off;
  const int* pd = g3 + off;  const int* pe = g4 + off;  const int* pf = g5 + off;

  i32x4 A[8], B[8], C[8];
  // ---- batch 1: graphs 0..2 (24 loads in flight) ----
  GLD8(A, pa); GLD8(B, pb); GLD8(C, pc);
  asm volatile("s_waitcnt vmcnt(0)" ::: "memory");
  __builtin_amdgcn_sched_barrier(0);
  unsigned v0 = packw(A) & keep;
  unsigned v1 = packw(B) & keep;
  unsigned v2 = packw(C) & keep;
  int stot = __popc(v0) + __popc(v1) + __popc(v2);
  size_t gq = (size_t)r * 16 + w;
  Gp[gq]                          = v0;
  Gp[gq + (size_t)(Bb * Nn) * 16] = v1;
  Gp[gq + (size_t)(Bb * Nn) * 32] = v2;
  // ---- batch 2: graphs 3..5 ----
  GLD8(A, pd); GLD8(B, pe); GLD8(C, pf);
  asm volatile("s_waitcnt vmcnt(0)" ::: "memory");
  __builtin_amdgcn_sched_barrier(0);
  unsigned v3 = packw(A) & keep;
  unsigned v4 = packw(B) & keep;
  unsigned v5 = packw(C) & keep;
  stot += __popc(v3) + __popc(v4) + __popc(v5);
  Gp[gq + (size_t)(Bb * Nn) * 48] = v3;
  Gp[gq + (size_t)(Bb * Nn) * 64] = v4;
  Gp[gq + (size_t)(Bb * Nn) * 80] = v5;

  stot += __shfl_xor(stot, 1);
  stot += __shfl_xor(stot, 2);
  stot += __shfl_xor(stot, 4);
  stot += __shfl_xor(stot, 8);
  if (w == 0)
    rs[r] = mask[r] ? 1.0f / (float)(stot < 1 ? 1 : stot) : 0.0f;
}
#undef GLD8
#undef GLD

// ---------------- K2: dw (sigmoid), Z node copy (bf16), X'^T build ---------
__global__ __launch_bounds__(256) void k_dw(
    const float* __restrict__ node, const int* __restrict__ mask,
    const float* __restrict__ wnw, const float* __restrict__ bnw,
    float* __restrict__ aw_out,    // already offset by t*N
    u16* __restrict__ Z, u16* __restrict__ XT){
  __shared__ float tile[32][268];
  __shared__ float dws[32];
  int b = blockIdx.x >> 4, n0 = (blockIdx.x & 15) << 5;
  int t = threadIdx.x;
  int row = t >> 3, seg = t & 7;
  const float* src = node + ((size_t)(b * Nn + n0 + row)) * Dd + seg * 32;
  u16* zn = Z + ((size_t)(b * Nn + n0 + row)) * KC + seg * 32;
  #pragma unroll
  for (int c = 0; c < 8; ++c){
    float4 v = ((const float4*)src)[c];
    tile[row][seg * 32 + c * 4 + 0] = v.x;
    tile[row][seg * 32 + c * 4 + 1] = v.y;
    tile[row][seg * 32 + c * 4 + 2] = v.z;
    tile[row][seg * 32 + c * 4 + 3] = v.w;
    ushort4 h;
    h.x = f2bf(v.x); h.y = f2bf(v.y); h.z = f2bf(v.z); h.w = f2bf(v.w);
    ((ushort4*)zn)[c] = h;
  }
  __syncthreads();
  float s = 0.f;
  #pragma unroll
  for (int c = 0; c < 32; ++c) s += tile[row][seg * 32 + c] * wnw[seg * 32 + c];
  s += __shfl_xor(s, 1); s += __shfl_xor(s, 2); s += __shfl_xor(s, 4);
  if (seg == 0){
    float dw = 1.f / (1.f + expf(-(s + bnw[0])));
    aw_out[b * (2 * Nn) + n0 + row] = dw;
    dws[row] = mask[b * Nn + n0 + row] ? dw : 0.f;
  }
  __syncthreads();
  #pragma unroll
  for (int p = 0; p < 4; ++p){
    int d = p * 64 + (t >> 2);
    int j0 = (t & 3) * 8;
    union { u16 h[8]; uint4 v; } pk;
    #pragma unroll
    for (int jj = 0; jj < 8; ++jj)
      pk.h[jj] = f2bf(dws[j0 + jj] * tile[j0 + jj][d]);
    *(uint4*)(XT + ((size_t)(b * Dd + d)) * Nn + n0 + j0) = pk.v;
  }
}

// ---------------- K3: aggregation GEMM  H'_k = rs * (G_k @ X') ------------
// grid (8, 32, 6): mtile, b, edge-type.  BM=64, BN=256(full D), BK=64, 4 waves
__global__ __launch_bounds__(256) void k_agg(
    const unsigned* __restrict__ Gp,
    const u16* __restrict__ XT, const float* __restrict__ rs,
    u16* __restrict__ Z){
  int mt = blockIdx.x, b = blockIdx.y, kg = blockIdx.z;
  int m0 = mt * 64;
  const unsigned* Gr = Gp + ((size_t)kg * Bb * Nn + b * Nn + m0) * 16;
  const u16* Xb = XT + (size_t)b * Dd * Nn;
  __shared__ u16 As[64 * 72];
  __shared__ u16 Bs[256 * 72];
  int t = threadIdx.x, lane = t & 63, wn = t >> 6;
  int arow = t >> 2, aq = t & 3;
  // preload this thread's 8 packed words (one per K-step), L2-hit
  unsigned wpre[8];
  #pragma unroll
  for (int ks = 0; ks < 8; ++ks)
    wpre[ks] = Gr[arow * 16 + ks * 2 + (aq >> 1)];

  f32x4 acc[4][4];
  #pragma unroll
  for (int i = 0; i < 4; ++i)
    #pragma unroll
    for (int q = 0; q < 4; ++q) acc[i][q] = (f32x4){0.f, 0.f, 0.f, 0.f};

  for (int ks = 0; ks < 8; ++ks){
    int k0 = ks * 64;
    { // A stage: unpack 16 bits -> bf16 0/1
      unsigned bits = (wpre[ks] >> ((aq & 1) * 16)) & 0xFFFFu;
      union { u16 h[16]; uint4 v[2]; } pk;
      #pragma unroll
      for (int c = 0; c < 16; ++c)
        pk.h[c] = ((bits >> c) & 1u) ? 0x3F80 : 0;
      *(uint4*)&As[arow * 72 + aq * 16]     = pk.v[0];
      *(uint4*)&As[arow * 72 + aq * 16 + 8] = pk.v[1];
    }
    // B stage: 256 rows (d) x 64 cols (n-slice) from X'^T
    #pragma unroll
    for (int p = 0; p < 8; ++p){
      int rowb = p * 32 + (t >> 3);
      *(uint4*)&Bs[rowb * 72 + (t & 7) * 8] =
          *(const uint4*)(Xb + (size_t)rowb * Nn + k0 + (t & 7) * 8);
    }
    __syncthreads();
    #pragma unroll
    for (int kk = 0; kk < 2; ++kk){
      bf16x8 av[4], bv[4];
      #pragma unroll
      for (int i = 0; i < 4; ++i)
        av[i] = *(const bf16x8*)&As[(i * 16 + (lane & 15)) * 72 + kk * 32 + (lane >> 4) * 8];
      #pragma unroll
      for (int q = 0; q < 4; ++q)
        bv[q] = *(const bf16x8*)&Bs[(wn * 64 + q * 16 + (lane & 15)) * 72 + kk * 32 + (lane >> 4) * 8];
      #pragma unroll
      for (int i = 0; i < 4; ++i)
        #pragma unroll
        for (int q = 0; q < 4; ++q)
          acc[i][q] = __builtin_amdgcn_mfma_f32_16x16x32_bf16(av[i], bv[q], acc[i][q], 0, 0, 0);
    }
    __syncthreads();
  }
  int kgcol = 256 + kg * 256 + wn * 64;
  #pragma unroll
  for (int i = 0; i < 4; ++i){
    #pragma unroll
    for (int r = 0; r < 4; ++r){
      int mg = m0 + i * 16 + (lane >> 4) * 4 + r;
      float sc = rs[b * Nn + mg];
      u16* zp = Z + ((size_t)(b * Nn + mg)) * KC + kgcol + (lane & 15);
      #pragma unroll
      for (int q = 0; q < 4; ++q)
        zp[q * 16] = f2bf(acc[i][q][r] * sc);
    }
  }
}

// ---------------- K4: update GEMM  out = relu(Z @ Wcat + b_self) ----------
// grid (2, 128): ntile, mtile. BM=128, BN=128, BK=64, 4 waves (2x2)
__global__ __launch_bounds__(256) void k_upd(
    const u16* __restrict__ Z, const u16* __restrict__ wcatT,
    const float* __restrict__ bself, float* __restrict__ outp){
  int n0 = blockIdx.x * 128, m0 = blockIdx.y * 128;
  __shared__ u16 As[128 * 72];
  __shared__ u16 Bs[128 * 72];
  int t = threadIdx.x, lane = t & 63, wid = t >> 6;
  int wm = wid >> 1, wn = wid & 1;
  f32x4 acc[4][4];
  #pragma unroll
  for (int i = 0; i < 4; ++i)
    #pragma unroll
    for (int q = 0; q < 4; ++q) acc[i][q] = (f32x4){0.f, 0.f, 0.f, 0.f};

  for (int ks = 0; ks < 28; ++ks){
    int k0 = ks * 64;
    #pragma unroll
    for (int p = 0; p < 4; ++p){
      int row = p * 32 + (t >> 3);
      *(uint4*)&As[row * 72 + (t & 7) * 8] =
          *(const uint4*)(Z + ((size_t)(m0 + row)) * KC + k0 + (t & 7) * 8);
      *(uint4*)&Bs[row * 72 + (t & 7) * 8] =
          *(const uint4*)(wcatT + ((size_t)(n0 + row)) * KC + k0 + (t & 7) * 8);
    }
    __syncthreads();
    #pragma unroll
    for (int kk = 0; kk < 2; ++kk){
      bf16x8 av[4], bv[4];
      #pragma unroll
      for (int i = 0; i < 4; ++i)
        av[i] = *(const bf16x8*)&As[(wm * 64 + i * 16 + (lane & 15)) * 72 + kk * 32 + (lane >> 4) * 8];
      #pragma unroll
      for (int q = 0; q < 4; ++q)
        bv[q] = *(const bf16x8*)&Bs[(wn * 64 + q * 16 + (lane & 15)) * 72 + kk * 32 + (lane >> 4) * 8];
      #pragma unroll
      for (int i = 0; i < 4; ++i)
        #pragma unroll
        for (int q = 0; q < 4; ++q)
          acc[i][q] = __builtin_amdgcn_mfma_f32_16x16x32_bf16(av[i], bv[q], acc[i][q], 0, 0, 0);
    }
    __syncthreads();
  }
  #pragma unroll
  for (int i = 0; i < 4; ++i){
    #pragma unroll
    for (int r = 0; r < 4; ++r){
      int mg = m0 + wm * 64 + i * 16 + (lane >> 4) * 4 + r;
      #pragma unroll
      for (int q = 0; q < 4; ++q){
        int e = n0 + wn * 64 + q * 16 + (lane & 15);
        float v = acc[i][q][r] + bself[e];
        outp[(size_t)mg * Dd + e] = v > 0.f ? v : 0.f;
      }
    }
  }
}

extern "C" void kernel_launch(void* const* d_in, const int* in_sizes, int n_in,
                              void* d_out, int out_size, void* d_ws, size_t ws_size,
                              hipStream_t stream){
  (void)in_sizes; (void)n_in; (void)out_size; (void)ws_size;
  const float* node  = (const float*)d_in[0];
  const int*   mask  = (const int*)d_in[1];
  const int*   g[6];
  for (int i = 0; i < 6; ++i) g[i] = (const int*)d_in[2 + i];
  const float* wnw   = (const float*)d_in[8];
  const float* bnw   = (const float*)d_in[9];
  const float* wself = (const float*)d_in[10];
  const float* bself = (const float*)d_in[11];
  const float* W[6];
  for (int i = 0; i < 6; ++i) W[i] = (const float*)d_in[12 + i];

  float* out_node = (float*)d_out;
  float* out_aw   = out_node + (size_t)Bb * Nn * Dd;

  char* ws = (char*)d_ws;
  u16*      wcatT = (u16*)(ws);                    // 917,504 B
  float*    rs    = (float*)(ws + 917504);         // 65,536 B
  unsigned* Mp    = (unsigned*)(ws + 983040);      // 2,048 B
  unsigned* Gp    = (unsigned*)(ws + 1048576);     // 6,291,456 B
  u16*      XT    = (u16*)(ws + 7340032);          // 8,388,608 B
  u16*      Z     = (u16*)(ws + 15728640);         // 58,720,256 B -> ends ~71 MB

  k_prep<<<256, 256, 0, stream>>>(wself, W[0], W[1], W[2], W[3], W[4], W[5], wcatT);
  k_mask<<<1, 512, 0, stream>>>(mask, Mp);
  k_pack<<<1024, 256, 0, stream>>>(g[0], g[1], g[2], g[3], g[4], g[5], mask, Mp, Gp, rs);

  for (int t = 0; t < 2; ++t){
    const float* nsrc = (t == 0) ? node : out_node;   // iter-1 result lives in d_out
    k_dw<<<512, 256, 0, stream>>>(nsrc, mask, wnw, bnw, out_aw + t * Nn, Z, XT);
    k_agg<<<dim3(8, 32, 6), 256, 0, stream>>>(Gp, XT, rs, Z);
    k_upd<<<dim3(2, 128), 256, 0, stream>>>(Z, wcatT, bself, out_node);
  }
}